// Round 1
// 379.818 us; speedup vs baseline: 1.0474x; 1.0474x over previous
//
#include <hip/hip_runtime.h>

// Problem constants
#define B_   4
#define L_   4096
#define D_   1024
#define ROWS (B_ * L_)     // 16384
#define K2   (2 * D_)      // 2048
#define BLD  (ROWS * D_)   // 16777216
#define CH   64            // chunk length for scan (vector-friendly)
#define NC   64            // chunks per sequence (CH*NC == L_)

typedef __attribute__((ext_vector_type(8))) short s8v;   // 8 x bf16 (4 VGPRs)
typedef __attribute__((ext_vector_type(4))) float f4v;   // 4 x f32 acc

// fp32 -> bf16, round-to-nearest-even
__device__ __forceinline__ unsigned short f2bf(float f) {
    unsigned int u = __float_as_uint(f);
    u += 0x7FFFu + ((u >> 16) & 1u);
    return (unsigned short)(u >> 16);
}

__device__ __forceinline__ float sigmoidf_(float v) {
    return 1.0f / (1.0f + __expf(-v));
}

// async 16B global -> LDS (wave-uniform LDS base + lane*16)
__device__ __forceinline__ void llds16(const void* g, void* l) {
    __builtin_amdgcn_global_load_lds(
        (const __attribute__((address_space(1))) unsigned int*)(g),
        (__attribute__((address_space(3))) unsigned int*)(l),
        16, 0, 0);
}

// ---------------- prefix-mean (2 passes, float4-vectorized) ----------------

// Pass 1: per-chunk partial sums. grid = B*NC = 256 blocks x 256 thr.
// Each thread owns 4 consecutive d (one float4); sums CH=64 rows.
__global__ void partial_sums(const float4* __restrict__ x4, float4* __restrict__ part4) {
    int bid = blockIdx.x;            // [0,256)
    int c = bid & 63, b = bid >> 6;
    int t = threadIdx.x;
    const float4* p = x4 + ((size_t)(b * L_ + c * CH) * 256 + t);
    float4 s; s.x = 0.f; s.y = 0.f; s.z = 0.f; s.w = 0.f;
#pragma unroll 8
    for (int i = 0; i < CH; ++i) {
        float4 v = p[(size_t)i * 256];
        s.x += v.x; s.y += v.y; s.z += v.z; s.w += v.w;
    }
    part4[(size_t)bid * 256 + t] = s;
}

// Pass 2 (fused chunk-scan + apply): block (b,c) re-sums partials of chunks
// [0,c) (independent parallel loads), then walks its CH rows computing the
// running mean via an LDS reciprocal table (no per-row fp32 divide).
// Writes avg (float4) and the bf16 GEMM A matrix [ROWS x 2048] as ushort4.
__global__ void apply_scan(const float4* __restrict__ x4, const float4* __restrict__ part4,
                           float4* __restrict__ avg4, ushort4* __restrict__ A4) {
    __shared__ float inv[CH];
    int bid = blockIdx.x;            // [0,256)
    int c = bid & 63, b = bid >> 6;
    int t = threadIdx.x;
    if (t < CH) inv[t] = 1.0f / (float)(c * CH + t + 1);

    // exclusive prefix over earlier chunks (uniform c per block, no divergence)
    float4 s; s.x = 0.f; s.y = 0.f; s.z = 0.f; s.w = 0.f;
    for (int cc = 0; cc < c; ++cc) {
        float4 v = part4[((size_t)(b * NC + cc)) * 256 + t];
        s.x += v.x; s.y += v.y; s.z += v.z; s.w += v.w;
    }
    __syncthreads();

    size_t row0 = (size_t)b * L_ + (size_t)c * CH;
    const float4* px = x4 + (row0 * 256 + t);
    float4*       pa = avg4 + (row0 * 256 + t);
    ushort4*      pA = A4 + (row0 * 512 + t);
#pragma unroll 4
    for (int i = 0; i < CH; ++i) {
        float4 v = px[(size_t)i * 256];
        s.x += v.x; s.y += v.y; s.z += v.z; s.w += v.w;
        float r = inv[i];
        float4 av; av.x = s.x * r; av.y = s.y * r; av.z = s.z * r; av.w = s.w * r;
        pa[(size_t)i * 256] = av;
        ushort4 ux; ux.x = f2bf(v.x);  ux.y = f2bf(v.y);  ux.z = f2bf(v.z);  ux.w = f2bf(v.w);
        ushort4 ua; ua.x = f2bf(av.x); ua.y = f2bf(av.y); ua.z = f2bf(av.z); ua.w = f2bf(av.w);
        pA[(size_t)i * 512]       = ux;
        pA[(size_t)i * 512 + 256] = ua;
    }
}

// W fp32 -> bf16, [2048 x 2048] row-major over e (== B^T layout, K contiguous)
__global__ void conv_w(const float4* __restrict__ W, ushort4* __restrict__ Wbf) {
    int t = blockIdx.x * 256 + threadIdx.x;   // [0, 1048576)
    float4 v = W[t];
    ushort4 o;
    o.x = f2bf(v.x); o.y = f2bf(v.y); o.z = f2bf(v.z); o.w = f2bf(v.w);
    Wbf[t] = o;
}

// ---------------- fused GEMM + gating (N-pair) ----------------
// Each block computes the 128x128 tiles for columns [col0,col0+128) of BOTH
// gate halves (e and e+1024), then applies sigmoid gating in-register and
// writes the final gating_outputs tile. 32 MFMAs per barrier pair.
__global__ __launch_bounds__(256, 2) void gemm_gated(
        const unsigned short* __restrict__ Abf, const unsigned short* __restrict__ Wbf,
        const float* __restrict__ x, const float* __restrict__ avg,
        const float* __restrict__ bg, float* __restrict__ out) {
    __shared__ __attribute__((aligned(16))) unsigned short sA [128 * 32];
    __shared__ __attribute__((aligned(16))) unsigned short sB0[128 * 32];
    __shared__ __attribute__((aligned(16))) unsigned short sB1[128 * 32];

    const int t    = threadIdx.x;
    const int w    = t >> 6;
    const int lane = t & 63;
    const int bid  = blockIdx.x;
    const int tileN = bid & 7, tileM = bid >> 3;     // 8 N-pairs x 128 M-tiles
    const int row0 = tileM * 128, col0 = tileN * 128;
    const int wm = w >> 1, wn = w & 1;
    const int quad = lane >> 4, lcol = lane & 15;

    f4v acc0[4][4], acc1[4][4];
#pragma unroll
    for (int i = 0; i < 4; ++i)
#pragma unroll
        for (int j = 0; j < 4; ++j)
#pragma unroll
            for (int r = 0; r < 4; ++r) { acc0[i][j][r] = 0.f; acc1[i][j][r] = 0.f; }

    // staging: 512 chunks of 16B per 128x32 tile; chunk c -> row c>>2, col (c&3)*8
    const int c0 = t, c1 = 256 + t;
    const unsigned short* gA0 = Abf + ((size_t)(row0 + (c0 >> 2)) * K2 + (c0 & 3) * 8);
    const unsigned short* gA1 = Abf + ((size_t)(row0 + (c1 >> 2)) * K2 + (c1 & 3) * 8);
    const unsigned short* gB0a = Wbf + ((size_t)(col0 + (c0 >> 2)) * K2 + (c0 & 3) * 8);
    const unsigned short* gB0b = Wbf + ((size_t)(col0 + (c1 >> 2)) * K2 + (c1 & 3) * 8);
    const unsigned short* gB1a = Wbf + ((size_t)(col0 + 1024 + (c0 >> 2)) * K2 + (c0 & 3) * 8);
    const unsigned short* gB1b = Wbf + ((size_t)(col0 + 1024 + (c1 >> 2)) * K2 + (c1 & 3) * 8);
    unsigned short* lA0  = &sA [w * 512];
    unsigned short* lA1  = &sA [2048 + w * 512];
    unsigned short* lB0a = &sB0[w * 512];
    unsigned short* lB0b = &sB0[2048 + w * 512];
    unsigned short* lB1a = &sB1[w * 512];
    unsigned short* lB1b = &sB1[2048 + w * 512];

    for (int k0 = 0; k0 < K2; k0 += 32) {
        __syncthreads();                       // protect LDS from overwrite
        llds16(gA0  + k0, lA0);
        llds16(gA1  + k0, lA1);
        llds16(gB0a + k0, lB0a);
        llds16(gB0b + k0, lB0b);
        llds16(gB1a + k0, lB1a);
        llds16(gB1b + k0, lB1b);
        __syncthreads();                       // drains vmcnt -> data ready

        s8v af[4], bf0[4], bf1[4];
#pragma unroll
        for (int i = 0; i < 4; ++i)
            af[i] = *(const s8v*)&sA[(wm * 64 + i * 16 + lcol) * 32 + quad * 8];
#pragma unroll
        for (int j = 0; j < 4; ++j) {
            bf0[j] = *(const s8v*)&sB0[(wn * 64 + j * 16 + lcol) * 32 + quad * 8];
            bf1[j] = *(const s8v*)&sB1[(wn * 64 + j * 16 + lcol) * 32 + quad * 8];
        }
#pragma unroll
        for (int i = 0; i < 4; ++i)
#pragma unroll
            for (int j = 0; j < 4; ++j) {
                acc0[i][j] = __builtin_amdgcn_mfma_f32_16x16x32_bf16(af[i], bf0[j], acc0[i][j], 0, 0, 0);
                acc1[i][j] = __builtin_amdgcn_mfma_f32_16x16x32_bf16(af[i], bf1[j], acc1[i][j], 0, 0, 0);
            }
    }

    // Epilogue: gating in-register. C/D layout: col = lane&15, row = quad*4 + reg
    float b1v[4], b2v[4];
#pragma unroll
    for (int j = 0; j < 4; ++j) {
        int cc = col0 + wn * 64 + j * 16 + lcol;
        b1v[j] = bg[cc];
        b2v[j] = bg[1024 + cc];
    }
#pragma unroll
    for (int i = 0; i < 4; ++i) {
#pragma unroll
        for (int j = 0; j < 4; ++j) {
            int rr = row0 + wm * 64 + i * 16 + quad * 4;
            int cc = col0 + wn * 64 + j * 16 + lcol;
#pragma unroll
            for (int r = 0; r < 4; ++r) {
                size_t off = (size_t)(rr + r) * D_ + cc;
                float gi = sigmoidf_(acc0[i][j][r] + b1v[j]);
                float gf = sigmoidf_(acc1[i][j][r] + b2v[j]);
                out[off] = gi * x[off] + gf * avg[off];
            }
        }
    }
}

extern "C" void kernel_launch(void* const* d_in, const int* in_sizes, int n_in,
                              void* d_out, int out_size, void* d_ws, size_t ws_size,
                              hipStream_t stream) {
    const float* x  = (const float*)d_in[0];   // [4,4096,1024]
    const float* W  = (const float*)d_in[1];   // [2048,2048]
    const float* bg = (const float*)d_in[2];   // [2048]
    float* out = (float*)d_out;                // [BLD gating | BLD avg]
    float* avg = out + (size_t)BLD;

    char* ws = (char*)d_ws;
    unsigned short* Abf = (unsigned short*)(ws);                      // 64 MB  [16384 x 2048] bf16
    unsigned short* Wbf = (unsigned short*)(ws + (size_t)67108864);   //  8 MB  [2048 x 2048] bf16
    // part (1 MB, [B x NC x D] f32) overlays the Wbf region: it is fully
    // consumed by apply_scan BEFORE conv_w writes Wbf. Footprint stays 72 MB.
    float4* prt4 = (float4*)(ws + (size_t)67108864);

    partial_sums<<<dim3(256), dim3(256), 0, stream>>>((const float4*)x, prt4);
    apply_scan<<<dim3(256), dim3(256), 0, stream>>>((const float4*)x, prt4,
                                                    (float4*)avg, (ushort4*)Abf);
    conv_w<<<dim3(4096), dim3(256), 0, stream>>>((const float4*)W, (ushort4*)Wbf);
    gemm_gated<<<dim3(1024), dim3(256), 0, stream>>>(Abf, Wbf, x, avg, bg, out);
}

// Round 2
// 365.661 us; speedup vs baseline: 1.0879x; 1.0387x over previous
//
#include <hip/hip_runtime.h>

// Problem constants
#define B_   4
#define L_   4096
#define D_   1024
#define ROWS (B_ * L_)     // 16384
#define K2   (2 * D_)      // 2048
#define BLD  (ROWS * D_)   // 16777216
#define CH   64            // chunk length for scan
#define NC   64            // chunks per sequence

typedef __attribute__((ext_vector_type(8))) short s8v;   // 8 x bf16
typedef __attribute__((ext_vector_type(4))) float f4v;   // 4 x f32 acc

__device__ __forceinline__ unsigned short f2bf(float f) {
    unsigned int u = __float_as_uint(f);
    u += 0x7FFFu + ((u >> 16) & 1u);
    return (unsigned short)(u >> 16);
}
__device__ __forceinline__ float sigmoidf_(float v) {
    return 1.0f / (1.0f + __expf(-v));
}
__device__ __forceinline__ void llds16(const void* g, void* l) {
    __builtin_amdgcn_global_load_lds(
        (const __attribute__((address_space(1))) unsigned int*)(g),
        (__attribute__((address_space(3))) unsigned int*)(l),
        16, 0, 0);
}
#define MEMFENCE asm volatile("" ::: "memory")
#define SBAR do { MEMFENCE; __builtin_amdgcn_s_barrier(); MEMFENCE; } while (0)

// ---------------- preprocessing ----------------

// Fused: blocks [0,256) = per-chunk partial sums; blocks [256,4352) = W->bf16.
__global__ void prep1(const float4* __restrict__ x4, float4* __restrict__ part4,
                      const float4* __restrict__ W, ushort4* __restrict__ Wbf) {
    int bid = blockIdx.x;
    int t = threadIdx.x;
    if (bid < 256) {
        int c = bid & 63, b = bid >> 6;
        const float4* p = x4 + ((size_t)(b * L_ + c * CH) * 256 + t);
        float4 s; s.x = 0.f; s.y = 0.f; s.z = 0.f; s.w = 0.f;
#pragma unroll 8
        for (int i = 0; i < CH; ++i) {
            float4 v = p[(size_t)i * 256];
            s.x += v.x; s.y += v.y; s.z += v.z; s.w += v.w;
        }
        part4[(size_t)bid * 256 + t] = s;
    } else {
        int i = (bid - 256) * 256 + t;     // [0, 1048576)
        float4 v = W[i];
        ushort4 o; o.x = f2bf(v.x); o.y = f2bf(v.y); o.z = f2bf(v.z); o.w = f2bf(v.w);
        Wbf[i] = o;
    }
}

// Fused chunk-scan + apply: writes avg (float4) and bf16 A matrix [ROWS x 2048].
__global__ void apply_scan(const float4* __restrict__ x4, const float4* __restrict__ part4,
                           float4* __restrict__ avg4, ushort4* __restrict__ A4) {
    __shared__ float inv[CH];
    int bid = blockIdx.x;            // [0,256)
    int c = bid & 63, b = bid >> 6;
    int t = threadIdx.x;
    if (t < CH) inv[t] = 1.0f / (float)(c * CH + t + 1);

    float4 s; s.x = 0.f; s.y = 0.f; s.z = 0.f; s.w = 0.f;
    for (int cc = 0; cc < c; ++cc) {
        float4 v = part4[((size_t)(b * NC + cc)) * 256 + t];
        s.x += v.x; s.y += v.y; s.z += v.z; s.w += v.w;
    }
    __syncthreads();

    size_t row0 = (size_t)b * L_ + (size_t)c * CH;
    const float4* px = x4 + (row0 * 256 + t);
    float4*       pa = avg4 + (row0 * 256 + t);
    ushort4*      pA = A4 + (row0 * 512 + t);
#pragma unroll 4
    for (int i = 0; i < CH; ++i) {
        float4 v = px[(size_t)i * 256];
        s.x += v.x; s.y += v.y; s.z += v.z; s.w += v.w;
        float r = inv[i];
        float4 av; av.x = s.x * r; av.y = s.y * r; av.z = s.z * r; av.w = s.w * r;
        pa[(size_t)i * 256] = av;
        ushort4 ux; ux.x = f2bf(v.x);  ux.y = f2bf(v.y);  ux.z = f2bf(v.z);  ux.w = f2bf(v.w);
        ushort4 ua; ua.x = f2bf(av.x); ua.y = f2bf(av.y); ua.z = f2bf(av.z); ua.w = f2bf(av.w);
        pA[(size_t)i * 512]       = ux;
        pA[(size_t)i * 512 + 256] = ua;
    }
}

// ---------------- 8-wave phased GEMM + gating ----------------
// Block: 512 threads = 8 waves (4M x 2N). Output: 256 rows x 128 cols x 2 halves.
// BK=32. LDS: 4-buffer ring, each buffer = A[256][32] + B[256][32] bf16 (32KB),
// total 128KB. K-tile tau read from buf[tau&3]; tile tau+3 staged into
// buf[(tau+3)&3] during tau (2 loads/phase). One counted vmcnt(8) per tile:
// retires exactly the 4 loads of the tile consumed next iteration (3-tile lead,
// 8-12 loads always in flight; never drains to 0).
// LDS swizzle: phys_byte = logical ^ ((row&3)<<4); staging applies the inverse
// permutation to the per-lane GLOBAL source (LDS dest stays linear: rule #21).
__global__ __launch_bounds__(512, 2) void gemm_gated8(
        const unsigned short* __restrict__ Abf, const unsigned short* __restrict__ Wbf,
        const float* __restrict__ x, const float* __restrict__ avg,
        const float* __restrict__ bg, float* __restrict__ out) {
    __shared__ __attribute__((aligned(16))) unsigned short S[4 * 2 * 8192]; // 128 KiB

    const int t    = threadIdx.x;          // 0..511
    const int w    = t >> 6;               // 0..7
    const int lane = t & 63;
    const int wm = w >> 1, wn = w & 1;     // 4M x 2N wave grid
    const int quad = lane >> 4, lcol = lane & 15;

    const int bid = blockIdx.x;            // 512 blocks, 512%8==0 -> bijective
    const int swz = (bid & 7) * 64 + (bid >> 3);     // XCD-contiguous
    const int tileN = swz & 7, tileM = swz >> 3;
    const int row0 = tileM * 256, col0 = tileN * 128;

    f4v acc0[4][4], acc1[4][4];
#pragma unroll
    for (int i = 0; i < 4; ++i)
#pragma unroll
        for (int j = 0; j < 4; ++j)
#pragma unroll
            for (int r = 0; r < 4; ++r) { acc0[i][j][r] = 0.f; acc1[i][j][r] = 0.f; }

    // ---- staging precompute: thread t owns granules q = t and q = 512+t ----
    // pre-swizzled source granule p = q ^ ((q>>2)&3)  (involution, 16B granules)
    const int qA0 = t, qA1 = 512 + t;
    const int p0 = qA0 ^ ((qA0 >> 2) & 3);
    const int p1 = qA1 ^ ((qA1 >> 2) & 3);
    const int m0 = p0 >> 2, k0e = (p0 & 3) * 8;      // A: row, k element offset
    const int m1 = p1 >> 2, k1e = (p1 & 3) * 8;
    const unsigned short* gA0 = Abf + (size_t)(row0 + m0) * K2 + k0e;
    const unsigned short* gA1 = Abf + (size_t)(row0 + m1) * K2 + k1e;
    const unsigned short* gB0 = Wbf + (size_t)(col0 + (m0 & 127) + (m0 >> 7) * 1024) * K2 + k0e;
    const unsigned short* gB1 = Wbf + (size_t)(col0 + (m1 & 127) + (m1 >> 7) * 1024) * K2 + k1e;

    // ---- LDS read offsets (ushort index), swizzled: byte ^= (row&3)<<4 ----
    int aoff[4], boff[2][4];
#pragma unroll
    for (int i = 0; i < 4; ++i)
        aoff[i] = ((((wm * 64 + i * 16 + lcol) * 64) + quad * 16) ^ ((lcol & 3) << 4)) >> 1;
#pragma unroll
    for (int h = 0; h < 2; ++h)
#pragma unroll
        for (int j = 0; j < 4; ++j)
            boff[h][j] = ((((h * 128 + wn * 64 + j * 16 + lcol) * 64) + quad * 16) ^ ((lcol & 3) << 4)) >> 1;

    // ---- prologue: stage tiles 0,1,2 into buffers 0,1,2 (12 loads/wave) ----
#pragma unroll
    for (int tt = 0; tt < 3; ++tt) {
        unsigned short* dA = S + tt * 16384;
        unsigned short* dB = S + tt * 16384 + 8192;
        llds16(gA0 + tt * 32, dA + qA0 * 8);
        llds16(gA1 + tt * 32, dA + qA1 * 8);
        llds16(gB0 + tt * 32, dB + qA0 * 8);
        llds16(gB1 + tt * 32, dB + qA1 * 8);
    }
    asm volatile("s_waitcnt vmcnt(8)" ::: "memory");  // tile 0 landed; 1,2 in flight
    SBAR;

    // ---- main loop: 64 K-tiles, 2 phases each ----
#pragma unroll 4
    for (int tau = 0; tau < 64; ++tau) {
        const unsigned short* bA = S + (tau & 3) * 16384;
        const unsigned short* bB = bA + 8192;
        const int st = tau + 3;
        unsigned short* dA = S + (st & 3) * 16384;
        unsigned short* dB = dA + 8192;
        const bool do_stage = st < 64;
        const int ko = st * 32;

        // ---- phase 1: A + B-half0 reads | stage A | 16 MFMA acc0 ----
        s8v af[4], bf[4];
#pragma unroll
        for (int i = 0; i < 4; ++i) af[i] = *(const s8v*)(bA + aoff[i]);
#pragma unroll
        for (int j = 0; j < 4; ++j) bf[j] = *(const s8v*)(bB + boff[0][j]);
        if (do_stage) {
            llds16(gA0 + ko, dA + qA0 * 8);
            llds16(gA1 + ko, dA + qA1 * 8);
        }
        SBAR;
        __builtin_amdgcn_s_setprio(1);
#pragma unroll
        for (int i = 0; i < 4; ++i)
#pragma unroll
            for (int j = 0; j < 4; ++j)
                acc0[i][j] = __builtin_amdgcn_mfma_f32_16x16x32_bf16(af[i], bf[j], acc0[i][j], 0, 0, 0);
        __builtin_amdgcn_s_setprio(0);
        SBAR;

        // ---- phase 2: B-half1 reads | stage B | vmcnt(8) | 16 MFMA acc1 ----
#pragma unroll
        for (int j = 0; j < 4; ++j) bf[j] = *(const s8v*)(bB + boff[1][j]);
        if (do_stage) {
            llds16(gB0 + ko, dB + qA0 * 8);
            llds16(gB1 + ko, dB + qA1 * 8);
        }
        asm volatile("s_waitcnt vmcnt(8)" ::: "memory");  // retire tile tau-2's loads
        SBAR;
        __builtin_amdgcn_s_setprio(1);
#pragma unroll
        for (int i = 0; i < 4; ++i)
#pragma unroll
            for (int j = 0; j < 4; ++j)
                acc1[i][j] = __builtin_amdgcn_mfma_f32_16x16x32_bf16(af[i], bf[j], acc1[i][j], 0, 0, 0);
        __builtin_amdgcn_s_setprio(0);
        SBAR;
    }

    // ---- epilogue: gating in-register. C/D: col = lane&15, row = quad*4+reg ----
    float b1v[4], b2v[4];
#pragma unroll
    for (int j = 0; j < 4; ++j) {
        int cc = col0 + wn * 64 + j * 16 + lcol;
        b1v[j] = bg[cc];
        b2v[j] = bg[1024 + cc];
    }
#pragma unroll
    for (int i = 0; i < 4; ++i) {
#pragma unroll
        for (int j = 0; j < 4; ++j) {
            int rr = row0 + wm * 64 + i * 16 + quad * 4;
            int cc = col0 + wn * 64 + j * 16 + lcol;
#pragma unroll
            for (int r = 0; r < 4; ++r) {
                size_t off = (size_t)(rr + r) * D_ + cc;
                float gi = sigmoidf_(acc0[i][j][r] + b1v[j]);
                float gf = sigmoidf_(acc1[i][j][r] + b2v[j]);
                out[off] = gi * x[off] + gf * avg[off];
            }
        }
    }
}

extern "C" void kernel_launch(void* const* d_in, const int* in_sizes, int n_in,
                              void* d_out, int out_size, void* d_ws, size_t ws_size,
                              hipStream_t stream) {
    const float* x  = (const float*)d_in[0];   // [4,4096,1024]
    const float* W  = (const float*)d_in[1];   // [2048,2048]
    const float* bg = (const float*)d_in[2];   // [2048]
    float* out = (float*)d_out;                // [BLD gating | BLD avg]
    float* avg = out + (size_t)BLD;

    char* ws = (char*)d_ws;
    unsigned short* Abf = (unsigned short*)(ws);                      // 64 MB [16384 x 2048] bf16
    unsigned short* Wbf = (unsigned short*)(ws + (size_t)67108864);   //  8 MB [2048 x 2048] bf16
    float4*         prt = (float4*)(ws + (size_t)75497472);           //  1 MB [B x NC x D] f32

    prep1<<<dim3(4352), dim3(256), 0, stream>>>((const float4*)x, prt,
                                                (const float4*)W, (ushort4*)Wbf);
    apply_scan<<<dim3(256), dim3(256), 0, stream>>>((const float4*)x, prt,
                                                    (float4*)avg, (ushort4*)Abf);
    gemm_gated8<<<dim3(512), dim3(512), 0, stream>>>(Abf, Wbf, x, avg, bg, out);
}

// Round 3
// 365.439 us; speedup vs baseline: 1.0886x; 1.0006x over previous
//
#include <hip/hip_runtime.h>

// Problem constants
#define B_   4
#define L_   4096
#define D_   1024
#define ROWS (B_ * L_)     // 16384
#define K2   (2 * D_)      // 2048
#define BLD  (ROWS * D_)   // 16777216
#define CH   64            // chunk length for scan
#define NC   64            // chunks per sequence

typedef __attribute__((ext_vector_type(8))) short s8v;   // 8 x bf16
typedef __attribute__((ext_vector_type(4))) float f4v;   // 4 x f32 acc

__device__ __forceinline__ unsigned short f2bf(float f) {
    unsigned int u = __float_as_uint(f);
    u += 0x7FFFu + ((u >> 16) & 1u);
    return (unsigned short)(u >> 16);
}
__device__ __forceinline__ float sigmoidf_(float v) {
    return 1.0f / (1.0f + __expf(-v));
}
__device__ __forceinline__ void llds16(const void* g, void* l) {
    __builtin_amdgcn_global_load_lds(
        (const __attribute__((address_space(1))) unsigned int*)(g),
        (__attribute__((address_space(3))) unsigned int*)(l),
        16, 0, 0);
}
#define MEMFENCE asm volatile("" ::: "memory")
#define SBAR do { MEMFENCE; __builtin_amdgcn_s_barrier(); MEMFENCE; } while (0)

// ---------------- preprocessing ----------------

// Fused: blocks [0,256) = per-chunk partial sums; blocks [256,4352) = W->bf16.
__global__ void prep1(const float4* __restrict__ x4, float4* __restrict__ part4,
                      const float4* __restrict__ W, ushort4* __restrict__ Wbf) {
    int bid = blockIdx.x;
    int t = threadIdx.x;
    if (bid < 256) {
        int c = bid & 63, b = bid >> 6;
        const float4* p = x4 + ((size_t)(b * L_ + c * CH) * 256 + t);
        float4 s; s.x = 0.f; s.y = 0.f; s.z = 0.f; s.w = 0.f;
#pragma unroll 8
        for (int i = 0; i < CH; ++i) {
            float4 v = p[(size_t)i * 256];
            s.x += v.x; s.y += v.y; s.z += v.z; s.w += v.w;
        }
        part4[(size_t)bid * 256 + t] = s;
    } else {
        int i = (bid - 256) * 256 + t;     // [0, 1048576)
        float4 v = W[i];
        ushort4 o; o.x = f2bf(v.x); o.y = f2bf(v.y); o.z = f2bf(v.z); o.w = f2bf(v.w);
        Wbf[i] = o;
    }
}

// Fused chunk-scan + apply: writes avg (float4) and bf16 A matrix [ROWS x 2048].
__global__ void apply_scan(const float4* __restrict__ x4, const float4* __restrict__ part4,
                           float4* __restrict__ avg4, ushort4* __restrict__ A4) {
    __shared__ float inv[CH];
    int bid = blockIdx.x;            // [0,256)
    int c = bid & 63, b = bid >> 6;
    int t = threadIdx.x;
    if (t < CH) inv[t] = 1.0f / (float)(c * CH + t + 1);

    float4 s; s.x = 0.f; s.y = 0.f; s.z = 0.f; s.w = 0.f;
    for (int cc = 0; cc < c; ++cc) {
        float4 v = part4[((size_t)(b * NC + cc)) * 256 + t];
        s.x += v.x; s.y += v.y; s.z += v.z; s.w += v.w;
    }
    __syncthreads();

    size_t row0 = (size_t)b * L_ + (size_t)c * CH;
    const float4* px = x4 + (row0 * 256 + t);
    float4*       pa = avg4 + (row0 * 256 + t);
    ushort4*      pA = A4 + (row0 * 512 + t);
#pragma unroll 4
    for (int i = 0; i < CH; ++i) {
        float4 v = px[(size_t)i * 256];
        s.x += v.x; s.y += v.y; s.z += v.z; s.w += v.w;
        float r = inv[i];
        float4 av; av.x = s.x * r; av.y = s.y * r; av.z = s.z * r; av.w = s.w * r;
        pa[(size_t)i * 256] = av;
        ushort4 ux; ux.x = f2bf(v.x);  ux.y = f2bf(v.y);  ux.z = f2bf(v.z);  ux.w = f2bf(v.w);
        ushort4 ua; ua.x = f2bf(av.x); ua.y = f2bf(av.y); ua.z = f2bf(av.z); ua.w = f2bf(av.w);
        pA[(size_t)i * 512]       = ux;
        pA[(size_t)i * 512 + 256] = ua;
    }
}

// ---------------- 8-wave phased GEMM + gating ----------------
// Block: 512 threads = 8 waves (4M x 2N). Output: 256 rows x 128 cols x 2 halves.
// BK=32. LDS: 4-buffer ring (128 KiB), 3-tile prefetch lead, counted vmcnt(8).
// LDS swizzle (corrected R3): phys_byte = logical ^ (((row>>1)&3)<<4).
//   Rationale: row stride = 64 B, so bank slot = {bit6 = row&1, bits[5:4]}.
//   XORing bits[5:4] with row bits [2:1] makes rows r..r+7 cover all 8
//   16B-slots -> conflict-free b128 octets (r vs r+8 alias 2-way = free).
//   R2's row bits [1:0] version left bit6 aliasing untouched (no-op, measured).
// Staging applies the inverse granule permutation q ^ ((q>>3)&3) to the
// per-lane GLOBAL source; LDS dest stays linear (rule #21).
__global__ __launch_bounds__(512, 2) void gemm_gated8(
        const unsigned short* __restrict__ Abf, const unsigned short* __restrict__ Wbf,
        const float* __restrict__ x, const float* __restrict__ avg,
        const float* __restrict__ bg, float* __restrict__ out) {
    __shared__ __attribute__((aligned(16))) unsigned short S[4 * 2 * 8192]; // 128 KiB

    const int t    = threadIdx.x;          // 0..511
    const int w    = t >> 6;               // 0..7
    const int lane = t & 63;
    const int wm = w >> 1, wn = w & 1;     // 4M x 2N wave grid
    const int quad = lane >> 4, lcol = lane & 15;

    const int bid = blockIdx.x;            // 512 blocks, 512%8==0 -> bijective
    const int swz = (bid & 7) * 64 + (bid >> 3);     // XCD-contiguous
    const int tileN = swz & 7, tileM = swz >> 3;
    const int row0 = tileM * 256, col0 = tileN * 128;

    f4v acc0[4][4], acc1[4][4];
#pragma unroll
    for (int i = 0; i < 4; ++i)
#pragma unroll
        for (int j = 0; j < 4; ++j)
#pragma unroll
            for (int r = 0; r < 4; ++r) { acc0[i][j][r] = 0.f; acc1[i][j][r] = 0.f; }

    // ---- staging precompute: thread t owns granules q = t and q = 512+t ----
    // source granule p = q ^ ((q>>3)&3)  (involution on 16B granules)
    const int qA0 = t, qA1 = 512 + t;
    const int p0 = qA0 ^ ((qA0 >> 3) & 3);
    const int p1 = qA1 ^ ((qA1 >> 3) & 3);
    const int m0 = p0 >> 2, k0e = (p0 & 3) * 8;      // A: row, k element offset
    const int m1 = p1 >> 2, k1e = (p1 & 3) * 8;
    const unsigned short* gA0 = Abf + (size_t)(row0 + m0) * K2 + k0e;
    const unsigned short* gA1 = Abf + (size_t)(row0 + m1) * K2 + k1e;
    const unsigned short* gB0 = Wbf + (size_t)(col0 + (m0 & 127) + (m0 >> 7) * 1024) * K2 + k0e;
    const unsigned short* gB1 = Wbf + (size_t)(col0 + (m1 & 127) + (m1 >> 7) * 1024) * K2 + k1e;

    // ---- LDS read offsets (ushort index), swizzled: byte ^= ((row>>1)&3)<<4 ----
    int aoff[4], boff[2][4];
#pragma unroll
    for (int i = 0; i < 4; ++i) {
        int ar = wm * 64 + i * 16 + lcol;
        aoff[i] = ((ar * 64 + quad * 16) ^ (((ar >> 1) & 3) << 4)) >> 1;
    }
#pragma unroll
    for (int h = 0; h < 2; ++h)
#pragma unroll
        for (int j = 0; j < 4; ++j) {
            int br = h * 128 + wn * 64 + j * 16 + lcol;
            boff[h][j] = ((br * 64 + quad * 16) ^ (((br >> 1) & 3) << 4)) >> 1;
        }

    // ---- prologue: stage tiles 0,1,2 into buffers 0,1,2 ----
#pragma unroll
    for (int tt = 0; tt < 3; ++tt) {
        unsigned short* dA = S + tt * 16384;
        unsigned short* dB = S + tt * 16384 + 8192;
        llds16(gA0 + tt * 32, dA + qA0 * 8);
        llds16(gA1 + tt * 32, dA + qA1 * 8);
        llds16(gB0 + tt * 32, dB + qA0 * 8);
        llds16(gB1 + tt * 32, dB + qA1 * 8);
    }
    asm volatile("s_waitcnt vmcnt(8)" ::: "memory");  // tile 0 landed; 1,2 in flight
    SBAR;

    // ---- main loop: 64 K-tiles, 2 phases each ----
#pragma unroll 4
    for (int tau = 0; tau < 64; ++tau) {
        const unsigned short* bA = S + (tau & 3) * 16384;
        const unsigned short* bB = bA + 8192;
        const int st = tau + 3;
        unsigned short* dA = S + (st & 3) * 16384;
        unsigned short* dB = dA + 8192;
        const bool do_stage = st < 64;
        const int ko = st * 32;

        // ---- phase 1: A + B-half0 reads | stage A | 16 MFMA acc0 ----
        s8v af[4], bf[4];
#pragma unroll
        for (int i = 0; i < 4; ++i) af[i] = *(const s8v*)(bA + aoff[i]);
#pragma unroll
        for (int j = 0; j < 4; ++j) bf[j] = *(const s8v*)(bB + boff[0][j]);
        if (do_stage) {
            llds16(gA0 + ko, dA + qA0 * 8);
            llds16(gA1 + ko, dA + qA1 * 8);
        }
        SBAR;
        __builtin_amdgcn_s_setprio(1);
#pragma unroll
        for (int i = 0; i < 4; ++i)
#pragma unroll
            for (int j = 0; j < 4; ++j)
                acc0[i][j] = __builtin_amdgcn_mfma_f32_16x16x32_bf16(af[i], bf[j], acc0[i][j], 0, 0, 0);
        __builtin_amdgcn_s_setprio(0);
        SBAR;

        // ---- phase 2: B-half1 reads | stage B | vmcnt(8) | 16 MFMA acc1 ----
#pragma unroll
        for (int j = 0; j < 4; ++j) bf[j] = *(const s8v*)(bB + boff[1][j]);
        if (do_stage) {
            llds16(gB0 + ko, dB + qA0 * 8);
            llds16(gB1 + ko, dB + qA1 * 8);
        }
        asm volatile("s_waitcnt vmcnt(8)" ::: "memory");  // retire tile tau-2's loads
        SBAR;
        __builtin_amdgcn_s_setprio(1);
#pragma unroll
        for (int i = 0; i < 4; ++i)
#pragma unroll
            for (int j = 0; j < 4; ++j)
                acc1[i][j] = __builtin_amdgcn_mfma_f32_16x16x32_bf16(af[i], bf[j], acc1[i][j], 0, 0, 0);
        __builtin_amdgcn_s_setprio(0);
        SBAR;
    }

    // ---- epilogue: gating in-register. C/D: col = lane&15, row = quad*4+reg ----
    float b1v[4], b2v[4];
#pragma unroll
    for (int j = 0; j < 4; ++j) {
        int cc = col0 + wn * 64 + j * 16 + lcol;
        b1v[j] = bg[cc];
        b2v[j] = bg[1024 + cc];
    }
#pragma unroll
    for (int i = 0; i < 4; ++i) {
#pragma unroll
        for (int j = 0; j < 4; ++j) {
            int rr = row0 + wm * 64 + i * 16 + quad * 4;
            int cc = col0 + wn * 64 + j * 16 + lcol;
#pragma unroll
            for (int r = 0; r < 4; ++r) {
                size_t off = (size_t)(rr + r) * D_ + cc;
                float gi = sigmoidf_(acc0[i][j][r] + b1v[j]);
                float gf = sigmoidf_(acc1[i][j][r] + b2v[j]);
                out[off] = gi * x[off] + gf * avg[off];
            }
        }
    }
}

extern "C" void kernel_launch(void* const* d_in, const int* in_sizes, int n_in,
                              void* d_out, int out_size, void* d_ws, size_t ws_size,
                              hipStream_t stream) {
    const float* x  = (const float*)d_in[0];   // [4,4096,1024]
    const float* W  = (const float*)d_in[1];   // [2048,2048]
    const float* bg = (const float*)d_in[2];   // [2048]
    float* out = (float*)d_out;                // [BLD gating | BLD avg]
    float* avg = out + (size_t)BLD;

    char* ws = (char*)d_ws;
    unsigned short* Abf = (unsigned short*)(ws);                      // 64 MB [16384 x 2048] bf16
    unsigned short* Wbf = (unsigned short*)(ws + (size_t)67108864);   //  8 MB [2048 x 2048] bf16
    float4*         prt = (float4*)(ws + (size_t)75497472);           //  1 MB [B x NC x D] f32

    prep1<<<dim3(4352), dim3(256), 0, stream>>>((const float4*)x, prt,
                                                (const float4*)W, (ushort4*)Wbf);
    apply_scan<<<dim3(256), dim3(256), 0, stream>>>((const float4*)x, prt,
                                                    (float4*)avg, (ushort4*)Abf);
    gemm_gated8<<<dim3(512), dim3(512), 0, stream>>>(Abf, Wbf, x, avg, bg, out);
}